// Round 9
// baseline (388.190 us; speedup 1.0000x reference)
//
#include <hip/hip_runtime.h>
#include <math.h>

#define DI __device__ __forceinline__

typedef unsigned short u16;
typedef __attribute__((ext_vector_type(8))) u16 u16x8;
typedef __attribute__((ext_vector_type(4))) u16 u16x4;
typedef __attribute__((ext_vector_type(8))) __bf16 bf16x8;
typedef __attribute__((ext_vector_type(4))) float f32x4;

typedef const __attribute__((address_space(1))) unsigned int g_u32;
typedef __attribute__((address_space(3))) unsigned int l_u32;

DI float bf2f(u16 u) {
  unsigned v = ((unsigned)u) << 16;
  float f; __builtin_memcpy(&f, &v, 4); return f;
}
DI u16 f2bf(float f) {
  unsigned u; __builtin_memcpy(&u, &f, 4);
  u += 0x7fff + ((u >> 16) & 1);   // RNE
  return (u16)(u >> 16);
}
DI f32x4 mfma16(bf16x8 a, bf16x8 b, f32x4 c) {
  return __builtin_amdgcn_mfma_f32_16x16x32_bf16(a, b, c, 0, 0, 0);
}
DI void gl16(const void* g, const u16* lds) {   // async global->LDS, 16B/lane
  __builtin_amdgcn_global_load_lds((g_u32*)g, (l_u32*)lds, 16, 0, 0);
}
DI unsigned cvtpk(float lo, float hi) {         // 2 f32 -> packed bf16 pair
  unsigned d;
  asm("v_cvt_pk_bf16_f32 %0, %1, %2" : "=v"(d) : "v"(lo), "v"(hi));
  return d;
}

// ---------------- conversion: fp32 -> bf16 (elementwise) ----------------
__global__ __launch_bounds__(256) void cvt_bf16_k(const float* __restrict__ in,
                                                  u16* __restrict__ out, int n) {
  int i = (blockIdx.x * 256 + threadIdx.x) * 8;
  if (i >= n) return;
  float4 a = *(const float4*)(in + i);
  float4 b = *(const float4*)(in + i + 4);
  u16x8 o;
  o[0] = f2bf(a.x); o[1] = f2bf(a.y); o[2] = f2bf(a.z); o[3] = f2bf(a.w);
  o[4] = f2bf(b.x); o[5] = f2bf(b.y); o[6] = f2bf(b.z); o[7] = f2bf(b.w);
  *(u16x8*)(out + i) = o;
}

// ---------------- conversion: fp32 [K][N] -> bf16 [N][K] (transpose) ----------------
__global__ __launch_bounds__(256) void tcvt_k(const float* __restrict__ in,
                                              u16* __restrict__ out, int K, int N) {
  __shared__ float tile[32][33];
  int n0 = blockIdx.x * 32, k0 = blockIdx.y * 32;
  int tx = threadIdx.x & 31, ty = threadIdx.x >> 5;  // 32 x 8
  #pragma unroll
  for (int i = 0; i < 4; i++) {
    int kr = ty + i * 8;
    tile[kr][tx] = in[(size_t)(k0 + kr) * N + n0 + tx];
  }
  __syncthreads();
  #pragma unroll
  for (int i = 0; i < 4; i++) {
    int nr = ty + i * 8;
    out[(size_t)(n0 + nr) * K + k0 + tx] = f2bf(tile[tx][nr]);
  }
}

__global__ __launch_bounds__(256) void pack_bias_k(const float* __restrict__ b0,
                                                   const float* __restrict__ b1,
                                                   const float* __restrict__ b2,
                                                   float* __restrict__ out) {
  int i = blockIdx.x * 256 + threadIdx.x;   // grid 12 -> 3072
  float v = (i < 1024) ? b0[i] : (i < 2048 ? b1[i - 1024] : b2[i - 2048]);
  out[i] = v;
}

// ---------------- V -> V^T per head: QKVb V-part -> VT[bh][64 d][512 kpos] ----------------
__global__ __launch_bounds__(256) void vtr_k(const u16* __restrict__ QKV,
                                             u16* __restrict__ VT) {
  __shared__ u16 tile[64][72];
  const int t = threadIdx.x;
  const int kt = blockIdx.x, bh = blockIdx.y;      // 8 x 128
  const int b = bh >> 4, h = bh & 15;
  {
    int r = t >> 2, d0 = (t & 3) * 16;
    const u16* src = &QKV[((size_t)(b * 512 + kt * 64 + r)) * 3072 + 2048 + h * 64 + d0];
    *(u16x8*)&tile[r][d0] = *(const u16x8*)src;
    *(u16x8*)&tile[r][d0 + 8] = *(const u16x8*)(src + 8);
  }
  __syncthreads();
  int d = t >> 2, kseg = (t & 3) * 16;
  u16x8 o0, o1;
  #pragma unroll
  for (int j = 0; j < 8; j++) { o0[j] = tile[kseg + j][d]; o1[j] = tile[kseg + 8 + j][d]; }
  u16* dst = &VT[((size_t)bh << 15) + (size_t)d * 512 + kt * 64 + kseg];
  *(u16x8*)dst = o0;
  *(u16x8*)(dst + 8) = o1;
}

// ================= 256x256 4-phase GEMM (T1+T2+T3+T4+T5) =================
// 8 waves; wave output = rows {ah*128 + wr*64 ..+64} x cols {bh*128 + wc*32 ..+32},
// so phase p touches exactly ONE new half-tile: P1=(A0,B0) P2=(A1,B0) P3=(A1,B1) P4=(A0,B1).
// Staging of tile t+1 spread 1 unit/phase into buf d^1 (prefetch distance >= 3 phases).
// Every wait is vmcnt(counted) + s_barrier => COLLECTIVE residency (r6 lesson: a per-wave
// vmcnt alone does NOT cover other waves' global_load_lds slices).
// T2 slot-rotation swizzle: 16B slot s of row r at slot (s+r)&7; 0 conflicts (r4-verified).
#define LD_A(half) do { const u16* Ah_ = &sA[d][half][0];                             \
  _Pragma("unroll") for (int i_ = 0; i_ < 4; i_++) {                                  \
    int row_ = wr * 64 + i_ * 16 + r15;                                               \
    _Pragma("unroll") for (int ks_ = 0; ks_ < 2; ks_++)                               \
      afr[i_][ks_] = *(const bf16x8*)&Ah_[row_ * 64 + (((ks_ * 4 + kg) + row_) & 7) * 8]; } \
} while (0)
#define LD_B(half) do { const u16* Bh_ = &sB[d][half][0];                             \
  _Pragma("unroll") for (int j_ = 0; j_ < 2; j_++) {                                  \
    int row_ = wc * 32 + j_ * 16 + r15;                                               \
    _Pragma("unroll") for (int ks_ = 0; ks_ < 2; ks_++)                               \
      bvr[j_][ks_] = *(const bf16x8*)&Bh_[row_ * 64 + (((ks_ * 4 + kg) + row_) & 7) * 8]; } \
} while (0)
#define MFMA_PH(ah, bh) do { __builtin_amdgcn_s_setprio(1);                           \
  _Pragma("unroll") for (int i_ = 0; i_ < 4; i_++)                                    \
    _Pragma("unroll") for (int j_ = 0; j_ < 2; j_++)                                  \
      _Pragma("unroll") for (int ks_ = 0; ks_ < 2; ks_++)                             \
        acc[(ah) * 4 + i_][(bh) * 2 + j_] =                                           \
            mfma16(afr[i_][ks_], bvr[j_][ks_], acc[(ah) * 4 + i_][(bh) * 2 + j_]);    \
  __builtin_amdgcn_s_setprio(0);                                                      \
} while (0)

template<int EPI, int SPLITK>
__global__ __launch_bounds__(512, 2) void gemm8p_k(const u16* __restrict__ A,
                                                   const u16* __restrict__ Bt,
                                                   const float* __restrict__ bias,
                                                   void* __restrict__ out,
                                                   int M, int N, int K) {
  __shared__ __align__(16) u16 sA[2][2][128 * 64];
  __shared__ __align__(16) u16 sB[2][2][128 * 64];
  const int tid = threadIdx.x;
  const int lane = tid & 63, wid = tid >> 6;
  const int wr = wid >> 2, wc = wid & 3;          // 2 x 4 waves
  const int r15 = lane & 15, kg = lane >> 4;

  // T1: bijective XCD swizzle (nwg % 8 == 0 for all our grids)
  const int GX = gridDim.x, GY = gridDim.y;
  int nwg = GX * GY;
  int orig = blockIdx.y * GX + blockIdx.x;
  int s = (orig & 7) * (nwg >> 3) + (orig >> 3);
  int bx = s / GY, by = s - bx * GY;
  const int bm = by * 256, bn = bx * 256;

  // split-K range
  const int z = blockIdx.z;
  int tilesK = K >> 6;
  int qs = tilesK / SPLITK, rs = tilesK - qs * SPLITK;
  int ntz = qs + (z < rs ? 1 : 0);
  int k0 = (z * qs + (z < rs ? z : rs)) << 6;

  f32x4 acc[8][4];
  #pragma unroll
  for (int i = 0; i < 8; i++)
    #pragma unroll
    for (int j = 0; j < 4; j++) acc[i][j] = (f32x4){0.f, 0.f, 0.f, 0.f};

  // staging pointers (slot-rotated source, linear LDS dest); each unit advances +64/tile
  const int drw = tid >> 3;
  const int gsl8 = ((tid - drw) & 7) << 3;
  const u16* pA0 = A  + (size_t)(bm +       drw) * K + k0 + gsl8;
  const u16* pA1 = A  + (size_t)(bm + 128 + drw) * K + k0 + gsl8;
  const u16* pB0 = Bt + (size_t)(bn +       drw) * K + k0 + gsl8;
  const u16* pB1 = Bt + (size_t)(bn + 128 + drw) * K + k0 + gsl8;
  const size_t s2o = (size_t)64 * K;
  const int dld = wid << 9;

  auto stA0 = [&](int d) { u16* D = &sA[d][0][dld]; gl16(pA0, D); gl16(pA0 + s2o, D + 4096); pA0 += 64; };
  auto stB0 = [&](int d) { u16* D = &sB[d][0][dld]; gl16(pB0, D); gl16(pB0 + s2o, D + 4096); pB0 += 64; };
  auto stA1 = [&](int d) { u16* D = &sA[d][1][dld]; gl16(pA1, D); gl16(pA1 + s2o, D + 4096); pA1 += 64; };
  auto stB1 = [&](int d) { u16* D = &sB[d][1][dld]; gl16(pB1, D); gl16(pB1 + s2o, D + 4096); pB1 += 64; };

  // prologue: tile 0 in issue order A0,B0,A1,B1 (= consumption order)
  stA0(0); stB0(0); stA1(0); stB1(0);

  for (int t = 0; t < ntz; ++t) {
    const int d = t & 1;
    const bool pf = (t + 1 < ntz);
    bf16x8 afr[4][2], bvr[2][2];

    // ---- P1: (A0,B0). queue [A0,B0,A1,B1] -> vmcnt(4) = A0,B0 landed ----
    asm volatile("s_waitcnt vmcnt(4)" ::: "memory");
    asm volatile("s_waitcnt lgkmcnt(0)" ::: "memory");   // my tile t-1 reads drained (WAR)
    __builtin_amdgcn_sched_barrier(0);
    __builtin_amdgcn_s_barrier();                        // collective: tile-t A0,B0 resident
    if (pf) stA0(d ^ 1);
    LD_A(0); LD_B(0);
    MFMA_PH(0, 0);
    // ---- P2: (A1,B0), reuse B0. queue [A1,B1,A0'] -> vmcnt(4) = A1 landed ----
    if (pf) { asm volatile("s_waitcnt vmcnt(4)" ::: "memory"); stB0(d ^ 1); }
    else    { asm volatile("s_waitcnt vmcnt(2)" ::: "memory"); }
    __builtin_amdgcn_s_barrier();                        // collective: A1 resident
    LD_A(1);
    MFMA_PH(1, 0);
    // ---- P3: (A1,B1), reuse A1. queue [B1,A0',B0'] -> vmcnt(4) = B1 landed ----
    if (pf) { asm volatile("s_waitcnt vmcnt(4)" ::: "memory"); stA1(d ^ 1); }
    else    { asm volatile("s_waitcnt vmcnt(0)" ::: "memory"); }
    __builtin_amdgcn_s_barrier();                        // collective: B1 resident
    LD_B(1);
    MFMA_PH(1, 1);
    // ---- P4: (A0,B1), reuse B1; A0 resident since P1 (no wait needed) ----
    if (pf) stB1(d ^ 1);
    LD_A(0);
    MFMA_PH(0, 1);
  }

  // epilogue: row = bm + ah*128 + wr*64 + i*16 + kg*4 ; col = bn + bh*128 + wc*32 + j*16 + r15
  #pragma unroll
  for (int ah = 0; ah < 2; ah++)
    #pragma unroll
    for (int ii = 0; ii < 4; ii++) {
      int row = bm + ah * 128 + wr * 64 + ii * 16 + kg * 4;
      #pragma unroll
      for (int bh = 0; bh < 2; bh++)
        #pragma unroll
        for (int jj = 0; jj < 2; jj++) {
          int col = bn + bh * 128 + wc * 32 + jj * 16 + r15;
          f32x4 av = acc[ah * 4 + ii][bh * 2 + jj];
          if (EPI == 4) {
            size_t zoff = (size_t)z * M * N;
            #pragma unroll
            for (int q2 = 0; q2 < 4; q2++)
              ((float*)out)[zoff + (size_t)(row + q2) * N + col] = av[q2];
          } else {
            float bv = bias[col];
            #pragma unroll
            for (int q2 = 0; q2 < 4; q2++) {
              float v = av[q2] + bv;
              if (EPI == 2) v = 0.5f * v * (1.0f + erff(v * 0.70710678118f));
              ((u16*)out)[(size_t)(row + q2) * N + col] = f2bf(v);
            }
          }
        }
    }
}

// ---------------- 128x128 counted-vmcnt GEMM (attn-dense) ----------------
template<int EPI>
__global__ __launch_bounds__(256) void gemm_bt_k(const u16* __restrict__ A,
                                                 const u16* __restrict__ Bt,
                                                 const float* __restrict__ bias,
                                                 const void* __restrict__ resid,
                                                 u16* __restrict__ out,
                                                 int M, int N, int K) {
  __shared__ __align__(16) u16 As[2][128 * 64];
  __shared__ __align__(16) u16 Bs[2][128 * 64];
  const int tid = threadIdx.x;
  const int lane = tid & 63, wid = tid >> 6;
  const int wm = (wid >> 1) * 64, wn = (wid & 1) * 64;
  const int r15 = lane & 15, kg = lane >> 4;
  const int srow = lane >> 3;

  const int GX = gridDim.x, GY = gridDim.y;
  int nwg = GX * GY;
  int orig = blockIdx.y * GX + blockIdx.x;
  int s = (orig & 7) * (nwg >> 3) + (orig >> 3);
  int bx = s / GY, by = s - bx * GY;
  const int bm = by * 128, bn = bx * 128;

  f32x4 acc[4][4];
  #pragma unroll
  for (int i = 0; i < 4; i++)
    #pragma unroll
    for (int j = 0; j < 4; j++) acc[i][j] = (f32x4){0.f, 0.f, 0.f, 0.f};

  const u16* pAc[4]; const u16* pBc[4];
  #pragma unroll
  for (int c = 0; c < 4; c++) {
    int chunk = (c << 2) | wid;
    int row = (chunk << 3) + srow;
    int gsl = ((lane & 7) - row) & 7;
    pAc[c] = A  + (size_t)(bm + row) * K + (gsl << 3);
    pBc[c] = Bt + (size_t)(bn + row) * K + (gsl << 3);
  }
  auto STAGE = [&](int buf, int kt) {
    #pragma unroll
    for (int c = 0; c < 4; c++) {
      int chunk = (c << 2) | wid;
      gl16(pAc[c] + kt, &As[buf][chunk << 9]);
      gl16(pBc[c] + kt, &Bs[buf][chunk << 9]);
    }
  };
  auto COMPUTE = [&](int buf) {
    #pragma unroll
    for (int ks = 0; ks < 2; ks++) {
      bf16x8 af[4], bfr[4];
      #pragma unroll
      for (int i = 0; i < 4; i++) {
        int row = wm + i * 16 + r15;
        af[i] = *(const bf16x8*)&As[buf][row * 64 + (((ks << 2) + kg + row) & 7) * 8];
      }
      #pragma unroll
      for (int i = 0; i < 4; i++) {
        int row = wn + i * 16 + r15;
        bfr[i] = *(const bf16x8*)&Bs[buf][row * 64 + (((ks << 2) + kg + row) & 7) * 8];
      }
      #pragma unroll
      for (int i = 0; i < 4; i++)
        #pragma unroll
        for (int j = 0; j < 4; j++)
          acc[i][j] = mfma16(af[i], bfr[j], acc[i][j]);
    }
  };

  const int nt = K >> 6;
  STAGE(0, 0);
  if (nt > 1) STAGE(1, 64);
  for (int t = 0; t < nt; ++t) {
    if (t + 1 < nt) asm volatile("s_waitcnt vmcnt(8)" ::: "memory");
    else            asm volatile("s_waitcnt vmcnt(0)" ::: "memory");
    __builtin_amdgcn_s_barrier();
    COMPUTE(t & 1);
    __builtin_amdgcn_s_barrier();
    __builtin_amdgcn_sched_barrier(0);
    if (t + 2 < nt) STAGE(t & 1, (t + 2) << 6);
  }

  #pragma unroll
  for (int i = 0; i < 4; i++) {
    int row0 = bm + wm + i * 16 + kg * 4;
    #pragma unroll
    for (int j = 0; j < 4; j++) {
      int col = bn + wn + j * 16 + r15;
      float bv = bias[col];
      #pragma unroll
      for (int q2 = 0; q2 < 4; q2++) {
        int row = row0 + q2;
        float v = acc[i][j][q2] + bv;
        if (EPI == 1) v += ((const float*)resid)[(size_t)row * N + col];
        out[(size_t)row * N + col] = f2bf(v);
      }
    }
  }
}

// ================= flash attention: swapped QK^T, in-register softmax =================
__global__ __launch_bounds__(256) void fattn_k(const u16* __restrict__ QKV,
                                               const u16* __restrict__ VT,
                                               const float* __restrict__ mask,
                                               u16* __restrict__ ctx) {
  __shared__ __align__(16) u16 sK[2][64 * 64];
  __shared__ __align__(16) u16 sV[2][64 * 64];
  __shared__ float sMask[512];
  const int t = threadIdx.x, lane = t & 63, wid = t >> 6;
  const int q15 = lane & 15, g = lane >> 4;
  const int qb = blockIdx.x, h = blockIdx.y, b = blockIdx.z;
  const int bh = b * 16 + h;
  const int qrow0 = qb * 128 + wid * 32;

  if (t < 128) *(float4*)&sMask[t * 4] = *(const float4*)&mask[b * 512 + t * 4];

  bf16x8 qf[2][2];
  #pragma unroll
  for (int qt = 0; qt < 2; qt++)
    #pragma unroll
    for (int c = 0; c < 2; c++)
      qf[qt][c] = *(const bf16x8*)&QKV[(size_t)(b * 512 + qrow0 + qt * 16 + q15) * 3072 +
                                       h * 64 + c * 32 + g * 8];

  const int srow0 = t >> 3;
  const int ssl = (((t & 7) - (t >> 3)) & 7) << 3;
  const u16* pK = QKV + (size_t)(b * 512 + srow0) * 3072 + 1024 + h * 64 + ssl;
  const u16* pV = VT + ((size_t)bh << 15) + (size_t)srow0 * 512 + ssl;
  const size_t kS2 = (size_t)32 * 3072;
  const size_t vS2 = (size_t)32 * 512;
  const int dld = t * 8;

  auto stage = [&](int d) {
    gl16(pK, &sK[d][dld]); gl16(pK + kS2, &sK[d][dld + 2048]);
    gl16(pV, &sV[d][dld]); gl16(pV + vS2, &sV[d][dld + 2048]);
    pK += 64 * 3072; pV += 64;
  };

  stage(0); stage(1);

  float m_[2] = {-1e30f, -1e30f}, l_[2] = {0.f, 0.f};
  f32x4 oacc[2][4];
  #pragma unroll
  for (int qt = 0; qt < 2; qt++)
    #pragma unroll
    for (int dt = 0; dt < 4; dt++) oacc[qt][dt] = (f32x4){0.f, 0.f, 0.f, 0.f};

  const int bp0 = ((g & 1) * 32 + q15) * 4;
  const int bp1 = bp0 + 64;

  for (int kt = 0; kt < 8; ++kt) {
    const int d = kt & 1;
    if (kt < 7) asm volatile("s_waitcnt vmcnt(4)" ::: "memory");
    else        asm volatile("s_waitcnt vmcnt(0)" ::: "memory");
    __builtin_amdgcn_s_barrier();

    f32x4 sc[2][4];
    #pragma unroll
    for (int qt = 0; qt < 2; qt++)
      #pragma unroll
      for (int k16 = 0; k16 < 4; k16++) sc[qt][k16] = (f32x4){0.f, 0.f, 0.f, 0.f};
    #pragma unroll
    for (int k16 = 0; k16 < 4; k16++) {
      int row = k16 * 16 + q15;
      bf16x8 ak0 = *(const bf16x8*)&sK[d][row * 64 + ((g + row) & 7) * 8];
      bf16x8 ak1 = *(const bf16x8*)&sK[d][row * 64 + ((4 + g + row) & 7) * 8];
      #pragma unroll
      for (int qt = 0; qt < 2; qt++) {
        sc[qt][k16] = mfma16(ak0, qf[qt][0], sc[qt][k16]);
        sc[qt][k16] = mfma16(ak1, qf[qt][1], sc[qt][k16]);
      }
    }

    float mk[4][4];
    #pragma unroll
    for (int k16 = 0; k16 < 4; k16++)
      #pragma unroll
      for (int r = 0; r < 4; r++)
        mk[k16][r] = sMask[kt * 64 + k16 * 16 + g * 4 + r];
    float p[2][16];
    #pragma unroll
    for (int qt = 0; qt < 2; qt++)
      #pragma unroll
      for (int k16 = 0; k16 < 4; k16++)
        #pragma unroll
        for (int r = 0; r < 4; r++)
          p[qt][k16 * 4 + r] = sc[qt][k16][r] * 0.125f + mk[k16][r];

    #pragma unroll
    for (int qt = 0; qt < 2; qt++) {
      float tmax = p[qt][0];
      #pragma unroll
      for (int j = 1; j < 16; j++) tmax = fmaxf(tmax, p[qt][j]);
      tmax = fmaxf(tmax, __shfl_xor(tmax, 16));
      tmax = fmaxf(tmax, __shfl_xor(tmax, 32));
      float mn = fmaxf(m_[qt], tmax);
      float al = __expf(m_[qt] - mn);
      m_[qt] = mn;
      float ts = 0.f;
      #pragma unroll
      for (int j = 0; j < 16; j++) { p[qt][j] = __expf(p[qt][j] - mn); ts += p[qt][j]; }
      ts += __shfl_xor(ts, 16);
      ts += __shfl_xor(ts, 32);
      l_[qt] = l_[qt] * al + ts;
      #pragma unroll
      for (int r = 0; r < 4; r++) {
        float alq = __shfl(al, g * 4 + r);
        #pragma unroll
        for (int dt = 0; dt < 4; dt++) oacc[qt][dt][r] *= alq;
      }
    }

    unsigned dwp[2][4][2];
    #pragma unroll
    for (int qt = 0; qt < 2; qt++)
      #pragma unroll
      for (int k16 = 0; k16 < 4; k16++) {
        dwp[qt][k16][0] = cvtpk(p[qt][k16 * 4 + 0], p[qt][k16 * 4 + 1]);
        dwp[qt][k16][1] = cvtpk(p[qt][k16 * 4 + 2], p[qt][k16 * 4 + 3]);
      }

    #pragma unroll
    for (int cp = 0; cp < 2; cp++) {
      bf16x8 pa[2];
      #pragma unroll
      for (int qt = 0; qt < 2; qt++) {
        union { unsigned u[4]; bf16x8 v; } pu;
        #pragma unroll
        for (int pp = 0; pp < 2; pp++) {
          unsigned a0 = __builtin_amdgcn_ds_bpermute(bp0, (int)dwp[qt][2 * cp][pp]);
          unsigned b0 = __builtin_amdgcn_ds_bpermute(bp0, (int)dwp[qt][2 * cp + 1][pp]);
          unsigned a1 = __builtin_amdgcn_ds_bpermute(bp1, (int)dwp[qt][2 * cp][pp]);
          unsigned b1 = __builtin_amdgcn_ds_bpermute(bp1, (int)dwp[qt][2 * cp + 1][pp]);
          pu.u[pp] = (g & 2) ? b0 : a0;
          pu.u[2 + pp] = (g & 2) ? b1 : a1;
        }
        pa[qt] = pu.v;
      }
      #pragma unroll
      for (int dt = 0; dt < 4; dt++) {
        int row = dt * 16 + q15;
        bf16x8 vf = *(const bf16x8*)&sV[d][row * 64 + (((cp << 2) + g + row) & 7) * 8];
        oacc[0][dt] = mfma16(pa[0], vf, oacc[0][dt]);
        oacc[1][dt] = mfma16(pa[1], vf, oacc[1][dt]);
      }
    }

    __builtin_amdgcn_s_barrier();
    __builtin_amdgcn_sched_barrier(0);
    if (kt + 2 < 8) stage(d);
  }

  #pragma unroll
  for (int qt = 0; qt < 2; qt++) {
    float linv[4];
    #pragma unroll
    for (int r = 0; r < 4; r++) linv[r] = 1.0f / __shfl(l_[qt], g * 4 + r);
    #pragma unroll
    for (int dt = 0; dt < 4; dt++)
      #pragma unroll
      for (int r = 0; r < 4; r++) {
        int row = qrow0 + qt * 16 + g * 4 + r;
        ctx[(size_t)(b * 512 + row) * 1024 + h * 64 + dt * 16 + q15] =
            f2bf(oacc[qt][dt][r] * linv[r]);
      }
  }
}

// ---------------- LayerNorm over rows of 1024 ----------------
template<int OUTF32>
__global__ __launch_bounds__(256) void ln_k(const u16* __restrict__ in,
                                            const float* __restrict__ g,
                                            const float* __restrict__ be,
                                            void* __restrict__ out) {
  int row = blockIdx.x, t = threadIdx.x;
  const u16* rp = in + (size_t)row * 1024 + t * 4;
  u16x4 raw = *(const u16x4*)rp;
  float x[4];
  #pragma unroll
  for (int i = 0; i < 4; i++) x[i] = bf2f(raw[i]);
  float s = x[0] + x[1] + x[2] + x[3];
  float q = x[0]*x[0] + x[1]*x[1] + x[2]*x[2] + x[3]*x[3];
  #pragma unroll
  for (int off = 32; off; off >>= 1) {
    s += __shfl_down(s, off);
    q += __shfl_down(q, off);
  }
  __shared__ float rs_[4], rq_[4];
  int wid = t >> 6, lane = t & 63;
  if (!lane) { rs_[wid] = s; rq_[wid] = q; }
  __syncthreads();
  float S1 = rs_[0] + rs_[1] + rs_[2] + rs_[3];
  float S2 = rq_[0] + rq_[1] + rq_[2] + rq_[3];
  float mu = S1 * (1.0f / 1024.0f);
  float inv = rsqrtf(S2 * (1.0f / 1024.0f) - mu * mu + 1e-5f);
  #pragma unroll
  for (int i = 0; i < 4; i++) {
    int c = t * 4 + i;
    float y = (x[i] - mu) * inv * g[c] + be[c];
    if (OUTF32) ((float*)out)[(size_t)row * 1024 + c] = y;
    else        ((u16*)out)[(size_t)row * 1024 + c] = f2bf(y);
  }
}

// ---------------- split-K reduce (3 partials) + bias + bf16 resid + LayerNorm -> fp32 ----------------
__global__ __launch_bounds__(256) void ln2r_k(const float* __restrict__ part,
                                              const float* __restrict__ bias,
                                              const u16* __restrict__ resid,
                                              const float* __restrict__ g,
                                              const float* __restrict__ be,
                                              float* __restrict__ out) {
  const int row = blockIdx.x, t = threadIdx.x;
  const size_t base = (size_t)row * 1024 + t * 4;
  float4 p0 = *(const float4*)(part + base);
  float4 p1 = *(const float4*)(part + 4194304 + base);
  float4 p2 = *(const float4*)(part + 8388608 + base);
  u16x4 rr = *(const u16x4*)(resid + base);
  float x[4];
  x[0] = p0.x + p1.x + p2.x + bias[t*4+0] + bf2f(rr[0]);
  x[1] = p0.y + p1.y + p2.y + bias[t*4+1] + bf2f(rr[1]);
  x[2] = p0.z + p1.z + p2.z + bias[t*4+2] + bf2f(rr[2]);
  x[3] = p0.w + p1.w + p2.w + bias[t*4+3] + bf2f(rr[3]);
  float s = x[0] + x[1] + x[2] + x[3];
  float q = x[0]*x[0] + x[1]*x[1] + x[2]*x[2] + x[3]*x[3];
  #pragma unroll
  for (int off = 32; off; off >>= 1) {
    s += __shfl_down(s, off);
    q += __shfl_down(q, off);
  }
  __shared__ float rs_[4], rq_[4];
  int wid = t >> 6, lane = t & 63;
  if (!lane) { rs_[wid] = s; rq_[wid] = q; }
  __syncthreads();
  float S1 = rs_[0] + rs_[1] + rs_[2] + rs_[3];
  float S2 = rq_[0] + rq_[1] + rq_[2] + rq_[3];
  float mu = S1 * (1.0f / 1024.0f);
  float inv = rsqrtf(S2 * (1.0f / 1024.0f) - mu * mu + 1e-5f);
  #pragma unroll
  for (int i = 0; i < 4; i++) {
    int c = t * 4 + i;
    out[(size_t)row * 1024 + c] = (x[i] - mu) * inv * g[c] + be[c];
  }
}

// ---------------- launch ----------------
extern "C" void kernel_launch(void* const* d_in, const int* in_sizes, int n_in,
                              void* d_out, int out_size, void* d_ws, size_t ws_size,
                              hipStream_t stream) {
  const float* hidden = (const float*)d_in[0];
  const float* mask   = (const float*)d_in[1];
  const float* wq  = (const float*)d_in[2];  const float* bq  = (const float*)d_in[3];
  const float* wk  = (const float*)d_in[4];  const float* bk  = (const float*)d_in[5];
  const float* wv  = (const float*)d_in[6];  const float* bv  = (const float*)d_in[7];
  const float* wo  = (const float*)d_in[8];  const float* bo  = (const float*)d_in[9];
  const float* ln1g = (const float*)d_in[10]; const float* ln1b = (const float*)d_in[11];
  const float* wi  = (const float*)d_in[12]; const float* bi  = (const float*)d_in[13];
  const float* wo2 = (const float*)d_in[14]; const float* bo2 = (const float*)d_in[15];
  const float* ln2g = (const float*)d_in[16]; const float* ln2b = (const float*)d_in[17];

  char* ws = (char*)d_ws;
  u16*   WqkvT = (u16*)(ws + 0);                 //  6291456  [3072][1024] bf16
  u16*   WoT   = (u16*)(ws + 6291456);           //  2097152
  u16*   Xb    = (u16*)(ws + 8388608);           //  8388608  [4096][1024] (dead after QKV gemm)
  u16*   VTb   = (u16*)(ws + 8388608);           //  8388608  [128 bh][64][512] (reuses Xb slot)
  u16*   QKVb  = (u16*)(ws + 16777216);          // 25165824  [4096][3072]
  u16*   Ctx   = (u16*)(ws + 41943040);          //  8388608
  u16*   AD    = (u16*)(ws + 50331648);          //  8388608
  float* part  = (float*)(ws + 0);               // 50331648  (overlaps dead region at FFN2 time)
  u16*   AO    = (u16*)(ws + 58720256);          //  8388608
  u16*   Inter = (u16*)(ws + 67108864);          // 33554432  [4096][4096]
  u16*   WiT   = (u16*)(ws + 100663296);         //  8388608  [4096][1024]
  u16*   Wo2T  = (u16*)(ws + 109051904);         //  8388608  [1024][4096]
  float* bqkv  = (float*)(ws + 117440512);       //    12288

  cvt_bf16_k<<<2048, 256, 0, stream>>>(hidden, Xb, 4194304);
  tcvt_k<<<dim3(32, 32),  256, 0, stream>>>(wq,  WqkvT,                1024, 1024);
  tcvt_k<<<dim3(32, 32),  256, 0, stream>>>(wk,  WqkvT + 1024 * 1024,  1024, 1024);
  tcvt_k<<<dim3(32, 32),  256, 0, stream>>>(wv,  WqkvT + 2048 * 1024,  1024, 1024);
  tcvt_k<<<dim3(32, 32),  256, 0, stream>>>(wo,  WoT,  1024, 1024);
  tcvt_k<<<dim3(128, 32), 256, 0, stream>>>(wi,  WiT,  1024, 4096);
  tcvt_k<<<dim3(32, 128), 256, 0, stream>>>(wo2, Wo2T, 4096, 1024);
  pack_bias_k<<<12, 256, 0, stream>>>(bq, bk, bv, bqkv);

  // QKV projection: [4096,1024] @ [1024,3072]
  gemm8p_k<0, 1><<<dim3(12, 16, 1), 512, 0, stream>>>(Xb, WqkvT, bqkv, QKVb, 4096, 3072, 1024);

  // V -> V^T per head (into dead Xb slot)
  vtr_k<<<dim3(8, 128), 256, 0, stream>>>(QKVb, VTb);

  // flash attention
  fattn_k<<<dim3(4, 16, 8), 256, 0, stream>>>(QKVb, VTb, mask, Ctx);

  // attn out-proj + f32 residual
  gemm_bt_k<1><<<dim3(8, 32), 256, 0, stream>>>(Ctx, WoT, bo, hidden, AD, 4096, 1024, 1024);
  ln_k<0><<<4096, 256, 0, stream>>>(AD, ln1g, ln1b, AO);

  // FFN1 + GELU: [4096,1024] @ [1024,4096]
  gemm8p_k<2, 1><<<dim3(16, 16, 1), 512, 0, stream>>>(AO, WiT, bi, Inter, 4096, 4096, 1024);

  // FFN2 split-K=3 partials: [4096,4096] @ [4096,1024]
  gemm8p_k<4, 3><<<dim3(4, 16, 3), 512, 0, stream>>>(Inter, Wo2T, nullptr, part, 4096, 1024, 4096);

  // reduce partials + bias + residual(AO) + LN2 -> fp32 out
  ln2r_k<<<4096, 256, 0, stream>>>(part, bo2, AO, ln2g, ln2b, (float*)d_out);
}